// Round 1
// baseline (1039.989 us; speedup 1.0000x reference)
//
#include <hip/hip_runtime.h>
#include <stdint.h>

#define T_TOK 8192
#define HD 2048
#define NE 8
#define FD 1408
#define BM 256              // rows per expert tile (padding to 256)
#define BK 32               // K-step (dbuf LDS fits in 64KB static)
#define MAXT 72             // max 256-row tiles: 16384/256 + 8
#define ROWS_CAP 18432      // 16384 + 8*256 padding

typedef unsigned short u16;
typedef __attribute__((ext_vector_type(8))) short bf16x8;   // 8 bf16 = 4 VGPRs
typedef __attribute__((ext_vector_type(4))) float f32x4;

__device__ __forceinline__ u16 f2bf(float f) {
  unsigned u = __float_as_uint(f);
  unsigned r = (u + 0x7fffu + ((u >> 16) & 1u)) >> 16;   // round-to-nearest-even
  return (u16)r;
}
__device__ __forceinline__ float bflo(unsigned u) { return __uint_as_float(u << 16); }
__device__ __forceinline__ float bfhi(unsigned u) { return __uint_as_float(u & 0xffff0000u); }

__device__ __forceinline__ void async_copy16(const void* g, void* l) {
  __builtin_amdgcn_global_load_lds(
      (__attribute__((address_space(1))) void*)(uintptr_t)g,
      (__attribute__((address_space(3))) void*)(uintptr_t)l,
      16, 0, 0);
}

__device__ __forceinline__ void conv4(const float* __restrict__ s, u16* __restrict__ d, long j) {
  float4 v = ((const float4*)s)[j];
  ushort4 o;
  o.x = f2bf(v.x); o.y = f2bf(v.y); o.z = f2bf(v.z); o.w = f2bf(v.w);
  ((ushort4*)d)[j] = o;
}

// ---------------- router (+ fused x->bf16 and weight fp32->bf16 conversion) ----------------
__global__ __launch_bounds__(256) void k_router(
    const float* __restrict__ x, const float* __restrict__ rw,
    const float* __restrict__ gw, const float* __restrict__ uw, const float* __restrict__ dw,
    u16* __restrict__ xb, u16* __restrict__ gwb, u16* __restrict__ uwb, u16* __restrict__ dwb,
    int* __restrict__ topk_idx, float* __restrict__ topk_w)
{
  int t = blockIdx.x;
  int tid = threadIdx.x;
  int lane = tid & 63;
  int wave = tid >> 6;               // wave w handles experts 2w, 2w+1
  const float4* xr = (const float4*)(x + (size_t)t * HD);
  const float4* w0 = (const float4*)(rw + (size_t)(wave * 2) * HD);
  const float4* w1 = (const float4*)(rw + (size_t)(wave * 2 + 1) * HD);
  float a0 = 0.f, a1 = 0.f;
  for (int i = lane; i < HD / 4; i += 64) {
    float4 xv = xr[i], v0 = w0[i], v1 = w1[i];
    a0 += xv.x * v0.x + xv.y * v0.y + xv.z * v0.z + xv.w * v0.w;
    a1 += xv.x * v1.x + xv.y * v1.y + xv.z * v1.z + xv.w * v1.w;
  }
  // fused x row -> bf16 (row is L1-hot)
  {
    float4 v0 = xr[tid * 2], v1 = xr[tid * 2 + 1];
    uint4 o;
    o.x = (unsigned)f2bf(v0.x) | ((unsigned)f2bf(v0.y) << 16);
    o.y = (unsigned)f2bf(v0.z) | ((unsigned)f2bf(v0.w) << 16);
    o.z = (unsigned)f2bf(v1.x) | ((unsigned)f2bf(v1.y) << 16);
    o.w = (unsigned)f2bf(v1.z) | ((unsigned)f2bf(v1.w) << 16);
    ((uint4*)(xb + (size_t)t * HD))[tid] = o;
  }
#pragma unroll
  for (int off = 32; off > 0; off >>= 1) {
    a0 += __shfl_down(a0, off);
    a1 += __shfl_down(a1, off);
  }
  __shared__ float lg[NE];
  if (lane == 0) { lg[wave * 2] = a0; lg[wave * 2 + 1] = a1; }
  __syncthreads();
  if (tid == 0) {
    float m1 = lg[0], m2 = -3.4e38f;
    int i1 = 0, i2 = 0;
    for (int e = 1; e < NE; e++) {
      float v = lg[e];
      if (v > m1)      { m2 = m1; i2 = i1; m1 = v; i1 = e; }
      else if (v > m2) { m2 = v; i2 = e; }
    }
    // normalized top-2 weights == 2-way softmax of top-2 logits
    float wA = 1.f / (1.f + expf(m2 - m1));
    float wB = 1.f - wA;
    topk_idx[t * 2] = i1; topk_idx[t * 2 + 1] = i2;
    topk_w[t * 2] = wA;   topk_w[t * 2 + 1] = wB;
  }
  // fused weight conversion: grid-stride over gate/up/down (overlaps router latency)
  const long n_w = (long)NE * FD * HD / 4;
  const long gstride = (long)gridDim.x * 256;
  const long g0 = (long)t * 256 + tid;
  for (long j = g0; j < n_w; j += gstride) conv4(gw, gwb, j);
  for (long j = g0; j < n_w; j += gstride) conv4(uw, uwb, j);
  for (long j = g0; j < n_w; j += gstride) conv4(dw, dwb, j);
}

// ---------------- meta+scatter: single block, prefix-scan, no global atomics ----------------
__global__ __launch_bounds__(256) void k_meta_scatter(
    const int* __restrict__ topk_idx, int* __restrict__ meta,
    int* __restrict__ row_token, int* __restrict__ tokrow)
{
  __shared__ int scan[NE][257];    // [e][0]=0; [e][tid+1]=thread count; then inclusive scan
  __shared__ int roff[NE], tstart[NE + 1];
  int tid = threadIdx.x;
  // zero row_token so padding rows map to token 0 (their Y rows are never read)
  for (int i = tid; i < ROWS_CAP; i += 256) row_token[i] = 0;
  if (tid < NE) scan[tid][0] = 0;
  // count: 64 contiguous items per thread
  int cnt[NE] = {};
  int base_i = tid * 64;
#pragma unroll 4
  for (int j = 0; j < 64; j++) {
    int v = topk_idx[base_i + j];
#pragma unroll
    for (int e = 0; e < NE; e++) cnt[e] += (v == e);
  }
  int i = tid + 1;
#pragma unroll
  for (int e = 0; e < NE; e++) scan[e][i] = cnt[e];
  __syncthreads();
  // Hillis-Steele inclusive scan over indices 1..256 (8 steps)
  for (int s = 1; s < 256; s <<= 1) {
    int add[NE];
#pragma unroll
    for (int e = 0; e < NE; e++) add[e] = (i >= s) ? scan[e][i - s] : 0;
    __syncthreads();
#pragma unroll
    for (int e = 0; e < NE; e++) scan[e][i] += add[e];
    __syncthreads();
  }
  if (tid == 0) {
    int off = 0, nt = 0;
    for (int e = 0; e < NE; e++) {
      int tot = scan[e][256];
      int tiles = (tot + BM - 1) / BM;
      roff[e] = off;
      tstart[e] = nt;
      nt += tiles;
      off += tiles * BM;           // expert regions padded to 256 rows
    }
    tstart[NE] = nt;
    meta[8] = nt;                  // total tiles
  }
  __syncthreads();
  int nt = tstart[NE];
  if (tid < nt) {
    int e = 0;
#pragma unroll
    for (int k = 1; k < NE; k++) e += (tid >= tstart[k]);
    meta[64 + tid] = e;                                 // tile -> expert
    meta[256 + tid] = roff[e] + (tid - tstart[e]) * BM; // tile -> row0
  }
  // placement: deterministic, no atomics
  int pos[NE];
#pragma unroll
  for (int e = 0; e < NE; e++) pos[e] = roff[e] + scan[e][tid];
  for (int j = 0; j < 64; j++) {
    int idx = base_i + j;
    int v = topk_idx[idx];
    int p = 0;
#pragma unroll
    for (int e = 0; e < NE; e++) if (v == e) p = pos[e]++;
    row_token[p] = idx >> 1;
    tokrow[idx] = p;
  }
}

// ---------------- grouped GEMM1: h = silu(x@gate^T) * (x@up^T), bf16 out ----------------
// BM=256 x BN=128, BK=32, 512 threads (8 waves as 4Mx2N, 64x64 per wave per matrix).
// Double-buffered LDS (T3-minimum pipeline): stage(next) -> compute(cur) -> one barrier.
// LDS layout is column-chunked [kslot][row] so fragment reads are 256B-contiguous per
// 16-lane group (zero bank conflicts) while global_load_lds dest stays linear.
__global__ __launch_bounds__(512, 2) void k_gemm1(
    const u16* __restrict__ xb, const u16* __restrict__ gwb, const u16* __restrict__ uwb,
    const int* __restrict__ meta, const int* __restrict__ row_token, u16* __restrict__ hb)
{
  int total = meta[8];
  int mt = (int)blockIdx.x;
  mt = (mt & 7) * 9 + (mt >> 3);     // chunked XCD swizzle, bijective (72 = 8*9)
  if (mt >= total) return;
  int e = meta[64 + mt];
  int row0 = meta[256 + mt];
  int ntile = blockIdx.y;

  __shared__ u16 As[2][BM * BK];     // 2 x 16KB, chunk d=16B: slot=d>>8, row=d&255
  __shared__ u16 Bgs[2][128 * BK];   // 2 x 8KB,  slot=d>>7, row=d&127
  __shared__ u16 Bus[2][128 * BK];   // 2 x 8KB   -> 64KB total static

  int tid = threadIdx.x;
  int lane = tid & 63;
  int wave = tid >> 6;               // 0..7
  int wr = wave >> 1, wc = wave & 1; // 4M x 2N

  // staging sources (column-chunked: source k-offset = slot*8 within the BK tile)
  int rowA = tid & 255;                       // same row both A rounds -> one gather
  int tok = row_token[row0 + rowA];
  const u16* aSrc0 = xb + (size_t)tok * HD + ((0 * 2 + (tid >> 8)) * 8);
  const u16* aSrc1 = xb + (size_t)tok * HD + ((1 * 2 + (tid >> 8)) * 8);
  int rowB = tid & 127;
  int slotB = tid >> 7;
  size_t wof = ((size_t)e * FD + (size_t)ntile * 128 + rowB) * HD + slotB * 8;
  const u16* gSrc = gwb + wof;
  const u16* uSrc = uwb + wof;
  const unsigned ldsA0 = (unsigned)((0 * 512 + wave * 64) * 16);
  const unsigned ldsA1 = (unsigned)((1 * 512 + wave * 64) * 16);
  const unsigned ldsB  = (unsigned)((wave * 64) * 16);

  // fragment read bases (chunk index; *16 = byte): [slot][row] layout, conflict-free
  const unsigned aRd = (unsigned)((lane >> 4) * 256 + wr * 64 + (lane & 15));
  const unsigned bRd = (unsigned)((lane >> 4) * 128 + wc * 64 + (lane & 15));

  f32x4 accG[4][4] = {};
  f32x4 accU[4][4] = {};

  // prologue: stage kt=0 into buffer 0
  {
    async_copy16(aSrc0, (char*)As[0] + ldsA0);
    async_copy16(aSrc1, (char*)As[0] + ldsA1);
    async_copy16(gSrc, (char*)Bgs[0] + ldsB);
    async_copy16(uSrc, (char*)Bus[0] + ldsB);
  }
  __syncthreads();

  int cur = 0;
  for (int kt = 0; kt < HD / BK; kt++) {     // 64 K-steps
    if (kt + 1 < HD / BK) {                  // issue next tile BEFORE compute
      int ko = (kt + 1) * BK;
      async_copy16(aSrc0 + ko, (char*)As[cur ^ 1] + ldsA0);
      async_copy16(aSrc1 + ko, (char*)As[cur ^ 1] + ldsA1);
      async_copy16(gSrc + ko, (char*)Bgs[cur ^ 1] + ldsB);
      async_copy16(uSrc + ko, (char*)Bus[cur ^ 1] + ldsB);
    }
    bf16x8 av[4], gv[4], uv[4];
#pragma unroll
    for (int mi = 0; mi < 4; mi++)
      av[mi] = *(const bf16x8*)((const char*)As[cur] + (aRd + mi * 16) * 16);
#pragma unroll
    for (int ni = 0; ni < 4; ni++) {
      gv[ni] = *(const bf16x8*)((const char*)Bgs[cur] + (bRd + ni * 16) * 16);
      uv[ni] = *(const bf16x8*)((const char*)Bus[cur] + (bRd + ni * 16) * 16);
    }
    __builtin_amdgcn_s_setprio(1);
#pragma unroll
    for (int mi = 0; mi < 4; mi++)
#pragma unroll
      for (int ni = 0; ni < 4; ni++) {
        accG[mi][ni] = __builtin_amdgcn_mfma_f32_16x16x32_bf16(av[mi], gv[ni], accG[mi][ni], 0, 0, 0);
        accU[mi][ni] = __builtin_amdgcn_mfma_f32_16x16x32_bf16(av[mi], uv[ni], accU[mi][ni], 0, 0, 0);
      }
    __builtin_amdgcn_s_setprio(0);
    __syncthreads();                         // single barrier: drains stage, guards reuse
    cur ^= 1;
  }

  // epilogue: silu(g)*u -> bf16 h. D layout: col=lane&15, row=(lane>>4)*4+reg
#pragma unroll
  for (int mi = 0; mi < 4; mi++) {
#pragma unroll
    for (int r = 0; r < 4; r++) {
      int row = row0 + wr * 64 + mi * 16 + (lane >> 4) * 4 + r;
      u16* hrow = hb + (size_t)row * FD + (size_t)ntile * 128 + wc * 64 + (lane & 15);
#pragma unroll
      for (int ni = 0; ni < 4; ni++) {
        float g = accG[mi][ni][r];
        float u = accU[mi][ni][r];
        float s = g / (1.f + __expf(-g));
        hrow[ni * 16] = f2bf(s * u);
      }
    }
  }
}

// ---------------- grouped GEMM2: Y = h @ down^T (row space, bf16, plain stores) ----------------
// BM=256 x BN=256, BK=32, 512 threads (8 waves as 2Mx4N, 128x64 per wave). Same dbuf pipeline.
__global__ __launch_bounds__(512, 2) void k_gemm2(
    const u16* __restrict__ hb, const u16* __restrict__ dwb,
    const int* __restrict__ meta, u16* __restrict__ Y)
{
  int total = meta[8];
  int mt = (int)blockIdx.x;
  mt = (mt & 7) * 9 + (mt >> 3);     // chunked XCD swizzle (72 = 8*9)
  if (mt >= total) return;
  int e = meta[64 + mt];
  int row0 = meta[256 + mt];
  int ntile = blockIdx.y;            // 0..7

  __shared__ u16 As[2][BM * BK];     // 2 x 16KB
  __shared__ u16 Bs[2][256 * BK];    // 2 x 16KB -> 64KB total static

  int tid = threadIdx.x;
  int lane = tid & 63;
  int wave = tid >> 6;
  int wr = wave >> 2, wc = wave & 3; // 2M x 4N: WM=128, WN=64

  int rowA = tid & 255;
  const u16* aSrc0 = hb + (size_t)(row0 + rowA) * FD + ((0 * 2 + (tid >> 8)) * 8);
  const u16* aSrc1 = hb + (size_t)(row0 + rowA) * FD + ((1 * 2 + (tid >> 8)) * 8);
  size_t bof = ((size_t)e * HD + (size_t)ntile * 256 + rowA) * FD;
  const u16* bSrc0 = dwb + bof + ((0 * 2 + (tid >> 8)) * 8);
  const u16* bSrc1 = dwb + bof + ((1 * 2 + (tid >> 8)) * 8);
  const unsigned lds0 = (unsigned)((0 * 512 + wave * 64) * 16);
  const unsigned lds1 = (unsigned)((1 * 512 + wave * 64) * 16);

  const unsigned aRd = (unsigned)((lane >> 4) * 256 + wr * 128 + (lane & 15));
  const unsigned bRd = (unsigned)((lane >> 4) * 256 + wc * 64 + (lane & 15));

  f32x4 acc[8][4] = {};

  {
    async_copy16(aSrc0, (char*)As[0] + lds0);
    async_copy16(aSrc1, (char*)As[0] + lds1);
    async_copy16(bSrc0, (char*)Bs[0] + lds0);
    async_copy16(bSrc1, (char*)Bs[0] + lds1);
  }
  __syncthreads();

  int cur = 0;
  for (int kt = 0; kt < FD / BK; kt++) {     // 44 K-steps
    if (kt + 1 < FD / BK) {
      int ko = (kt + 1) * BK;
      async_copy16(aSrc0 + ko, (char*)As[cur ^ 1] + lds0);
      async_copy16(aSrc1 + ko, (char*)As[cur ^ 1] + lds1);
      async_copy16(bSrc0 + ko, (char*)Bs[cur ^ 1] + lds0);
      async_copy16(bSrc1 + ko, (char*)Bs[cur ^ 1] + lds1);
    }
    bf16x8 av[8], bv[4];
#pragma unroll
    for (int mi = 0; mi < 8; mi++)
      av[mi] = *(const bf16x8*)((const char*)As[cur] + (aRd + mi * 16) * 16);
#pragma unroll
    for (int ni = 0; ni < 4; ni++)
      bv[ni] = *(const bf16x8*)((const char*)Bs[cur] + (bRd + ni * 16) * 16);
    __builtin_amdgcn_s_setprio(1);
#pragma unroll
    for (int mi = 0; mi < 8; mi++)
#pragma unroll
      for (int ni = 0; ni < 4; ni++)
        acc[mi][ni] = __builtin_amdgcn_mfma_f32_16x16x32_bf16(av[mi], bv[ni], acc[mi][ni], 0, 0, 0);
    __builtin_amdgcn_s_setprio(0);
    __syncthreads();
    cur ^= 1;
  }

  // epilogue: plain bf16 stores into row-space Y
#pragma unroll
  for (int mi = 0; mi < 8; mi++) {
#pragma unroll
    for (int r = 0; r < 4; r++) {
      int grow = row0 + wr * 128 + mi * 16 + (lane >> 4) * 4 + r;
      u16* yrow = Y + (size_t)grow * HD + (size_t)ntile * 256 + wc * 64 + (lane & 15);
#pragma unroll
      for (int ni = 0; ni < 4; ni++)
        yrow[ni * 16] = f2bf(acc[mi][ni][r]);
    }
  }
}

// ---------------- combine: out[t] = wA*Y[rowA] + wB*Y[rowB] ----------------
__global__ __launch_bounds__(256) void k_combine(
    const u16* __restrict__ Y, const int* __restrict__ tokrow,
    const float* __restrict__ topk_w, float* __restrict__ out)
{
  int t = blockIdx.x;
  int i = threadIdx.x;               // 256 threads x 8 cols = 2048
  int rA = tokrow[t * 2], rB = tokrow[t * 2 + 1];
  float wA = topk_w[t * 2], wB = topk_w[t * 2 + 1];
  uint4 a = *(const uint4*)(Y + (size_t)rA * HD + i * 8);
  uint4 b = *(const uint4*)(Y + (size_t)rB * HD + i * 8);
  float4 o0, o1;
  o0.x = wA * bflo(a.x) + wB * bflo(b.x);
  o0.y = wA * bfhi(a.x) + wB * bfhi(b.x);
  o0.z = wA * bflo(a.y) + wB * bflo(b.y);
  o0.w = wA * bfhi(a.y) + wB * bfhi(b.y);
  o1.x = wA * bflo(a.z) + wB * bflo(b.z);
  o1.y = wA * bfhi(a.z) + wB * bfhi(b.z);
  o1.z = wA * bflo(a.w) + wB * bflo(b.w);
  o1.w = wA * bfhi(a.w) + wB * bfhi(b.w);
  float* op = out + (size_t)t * HD + i * 8;
  *(float4*)op = o0;
  *(float4*)(op + 4) = o1;
}

extern "C" void kernel_launch(void* const* d_in, const int* in_sizes, int n_in,
                              void* d_out, int out_size, void* d_ws, size_t ws_size,
                              hipStream_t stream) {
  const float* x  = (const float*)d_in[0];
  const float* rw = (const float*)d_in[1];
  const float* gw = (const float*)d_in[2];
  const float* uw = (const float*)d_in[3];
  const float* dw = (const float*)d_in[4];
  float* out = (float*)d_out;

  char* w = (char*)d_ws;
  int*   meta      = (int*)w;                                    // 4KB meta block
  int*   row_token = (int*)(w + 4096);
  int*   topk_idx  = (int*)(w + 4096 + ROWS_CAP * 4);
  float* topk_w    = (float*)(w + 4096 + ROWS_CAP * 4 + T_TOK * 2 * 4);
  int*   tokrow    = (int*)(w + 4096 + ROWS_CAP * 4 + T_TOK * 4 * 4);
  size_t off = (size_t)1 << 20;
  u16* xb  = (u16*)(w + off); off += (size_t)T_TOK * HD * 2;     // 33.5 MB
  u16* gwb = (u16*)(w + off); off += (size_t)NE * FD * HD * 2;   // 46.1 MB
  u16* uwb = (u16*)(w + off); off += (size_t)NE * FD * HD * 2;   // 46.1 MB
  u16* dwb = (u16*)(w + off); off += (size_t)NE * HD * FD * 2;   // 46.1 MB
  u16* hb  = (u16*)(w + off);                                    // 51.9 MB
  // Y (75.5 MB) aliases xb+gwb (79.7 MB) — both dead once gemm1 completes,
  // and the stream serializes gemm1 -> gemm2 -> combine.
  u16* Y = xb;

  k_router<<<T_TOK, 256, 0, stream>>>(x, rw, gw, uw, dw, xb, gwb, uwb, dwb, topk_idx, topk_w);
  k_meta_scatter<<<1, 256, 0, stream>>>(topk_idx, meta, row_token, tokrow);
  k_gemm1<<<dim3(MAXT, FD / 128), 512, 0, stream>>>(xb, gwb, uwb, meta, row_token, hb);
  k_gemm2<<<dim3(MAXT, HD / 256), 512, 0, stream>>>(hb, dwb, meta, Y);
  k_combine<<<T_TOK, 256, 0, stream>>>(Y, tokrow, topk_w, out);
}

// Round 2
// 747.675 us; speedup vs baseline: 1.3910x; 1.3910x over previous
//
#include <hip/hip_runtime.h>
#include <stdint.h>

#define T_TOK 8192
#define HD 2048
#define NE 8
#define FD 1408
#define BM 256              // rows per expert tile (padding to 256)
#define BN1 128             // gemm1 N tile
#define BN2 128             // gemm2 N tile
#define BK 64               // K-step
#define MAXT 72             // max 256-row tiles: 16384/256 + 8
#define ROWS_CAP 18432      // 16384 + 8*256 padding

typedef unsigned short u16;
typedef __attribute__((ext_vector_type(8))) short bf16x8;   // 8 bf16 = 4 VGPRs
typedef __attribute__((ext_vector_type(4))) float f32x4;

__device__ __forceinline__ u16 f2bf(float f) {
  unsigned u = __float_as_uint(f);
  unsigned r = (u + 0x7fffu + ((u >> 16) & 1u)) >> 16;   // round-to-nearest-even
  return (u16)r;
}
__device__ __forceinline__ float bflo(unsigned u) { return __uint_as_float(u << 16); }
__device__ __forceinline__ float bfhi(unsigned u) { return __uint_as_float(u & 0xffff0000u); }

__device__ __forceinline__ void async_copy16(const void* g, void* l) {
  __builtin_amdgcn_global_load_lds(
      (__attribute__((address_space(1))) void*)(uintptr_t)g,
      (__attribute__((address_space(3))) void*)(uintptr_t)l,
      16, 0, 0);
}

__device__ __forceinline__ void conv4(const float* __restrict__ s, u16* __restrict__ d, long j) {
  float4 v = ((const float4*)s)[j];
  ushort4 o;
  o.x = f2bf(v.x); o.y = f2bf(v.y); o.z = f2bf(v.z); o.w = f2bf(v.w);
  ((ushort4*)d)[j] = o;
}

// ---------------- router (+ fused x->bf16 and weight fp32->bf16 conversion) ----------------
__global__ __launch_bounds__(256) void k_router(
    const float* __restrict__ x, const float* __restrict__ rw,
    const float* __restrict__ gw, const float* __restrict__ uw, const float* __restrict__ dw,
    u16* __restrict__ xb, u16* __restrict__ gwb, u16* __restrict__ uwb, u16* __restrict__ dwb,
    int* __restrict__ topk_idx, float* __restrict__ topk_w)
{
  int t = blockIdx.x;
  int tid = threadIdx.x;
  int lane = tid & 63;
  int wave = tid >> 6;               // wave w handles experts 2w, 2w+1
  const float4* xr = (const float4*)(x + (size_t)t * HD);
  const float4* w0 = (const float4*)(rw + (size_t)(wave * 2) * HD);
  const float4* w1 = (const float4*)(rw + (size_t)(wave * 2 + 1) * HD);
  float a0 = 0.f, a1 = 0.f;
  for (int i = lane; i < HD / 4; i += 64) {
    float4 xv = xr[i], v0 = w0[i], v1 = w1[i];
    a0 += xv.x * v0.x + xv.y * v0.y + xv.z * v0.z + xv.w * v0.w;
    a1 += xv.x * v1.x + xv.y * v1.y + xv.z * v1.z + xv.w * v1.w;
  }
  // fused x row -> bf16 (row is L1-hot)
  {
    float4 v0 = xr[tid * 2], v1 = xr[tid * 2 + 1];
    uint4 o;
    o.x = (unsigned)f2bf(v0.x) | ((unsigned)f2bf(v0.y) << 16);
    o.y = (unsigned)f2bf(v0.z) | ((unsigned)f2bf(v0.w) << 16);
    o.z = (unsigned)f2bf(v1.x) | ((unsigned)f2bf(v1.y) << 16);
    o.w = (unsigned)f2bf(v1.z) | ((unsigned)f2bf(v1.w) << 16);
    ((uint4*)(xb + (size_t)t * HD))[tid] = o;
  }
#pragma unroll
  for (int off = 32; off > 0; off >>= 1) {
    a0 += __shfl_down(a0, off);
    a1 += __shfl_down(a1, off);
  }
  __shared__ float lg[NE];
  if (lane == 0) { lg[wave * 2] = a0; lg[wave * 2 + 1] = a1; }
  __syncthreads();
  if (tid == 0) {
    float m1 = lg[0], m2 = -3.4e38f;
    int i1 = 0, i2 = 0;
    for (int e = 1; e < NE; e++) {
      float v = lg[e];
      if (v > m1)      { m2 = m1; i2 = i1; m1 = v; i1 = e; }
      else if (v > m2) { m2 = v; i2 = e; }
    }
    // normalized top-2 weights == 2-way softmax of top-2 logits
    float wA = 1.f / (1.f + expf(m2 - m1));
    float wB = 1.f - wA;
    topk_idx[t * 2] = i1; topk_idx[t * 2 + 1] = i2;
    topk_w[t * 2] = wA;   topk_w[t * 2 + 1] = wB;
  }
  // fused weight conversion: grid-stride over gate/up/down (overlaps router latency)
  const long n_w = (long)NE * FD * HD / 4;
  const long gstride = (long)gridDim.x * 256;
  const long g0 = (long)t * 256 + tid;
  for (long j = g0; j < n_w; j += gstride) conv4(gw, gwb, j);
  for (long j = g0; j < n_w; j += gstride) conv4(uw, uwb, j);
  for (long j = g0; j < n_w; j += gstride) conv4(dw, dwb, j);
}

// ---------------- meta+scatter: single block, prefix-scan, no global atomics ----------------
__global__ __launch_bounds__(256) void k_meta_scatter(
    const int* __restrict__ topk_idx, int* __restrict__ meta,
    int* __restrict__ row_token, int* __restrict__ tokrow)
{
  __shared__ int scan[NE][257];    // [e][0]=0; [e][tid+1]=thread count; then inclusive scan
  __shared__ int roff[NE], tstart[NE + 1];
  int tid = threadIdx.x;
  // zero row_token so padding rows map to token 0 (their Y rows are never read)
  for (int i = tid; i < ROWS_CAP; i += 256) row_token[i] = 0;
  if (tid < NE) scan[tid][0] = 0;
  // count: 64 contiguous items per thread
  int cnt[NE] = {};
  int base_i = tid * 64;
#pragma unroll 4
  for (int j = 0; j < 64; j++) {
    int v = topk_idx[base_i + j];
#pragma unroll
    for (int e = 0; e < NE; e++) cnt[e] += (v == e);
  }
  int i = tid + 1;
#pragma unroll
  for (int e = 0; e < NE; e++) scan[e][i] = cnt[e];
  __syncthreads();
  // Hillis-Steele inclusive scan over indices 1..256 (8 steps)
  for (int s = 1; s < 256; s <<= 1) {
    int add[NE];
#pragma unroll
    for (int e = 0; e < NE; e++) add[e] = (i >= s) ? scan[e][i - s] : 0;
    __syncthreads();
#pragma unroll
    for (int e = 0; e < NE; e++) scan[e][i] += add[e];
    __syncthreads();
  }
  if (tid == 0) {
    int off = 0, nt = 0;
    for (int e = 0; e < NE; e++) {
      int tot = scan[e][256];
      int tiles = (tot + BM - 1) / BM;
      roff[e] = off;
      tstart[e] = nt;
      nt += tiles;
      off += tiles * BM;           // expert regions padded to 256 rows
    }
    tstart[NE] = nt;
    meta[8] = nt;                  // total tiles
  }
  __syncthreads();
  int nt = tstart[NE];
  if (tid < nt) {
    int e = 0;
#pragma unroll
    for (int k = 1; k < NE; k++) e += (tid >= tstart[k]);
    meta[64 + tid] = e;                                 // tile -> expert
    meta[256 + tid] = roff[e] + (tid - tstart[e]) * BM; // tile -> row0
  }
  // placement: deterministic, no atomics
  int pos[NE];
#pragma unroll
  for (int e = 0; e < NE; e++) pos[e] = roff[e] + scan[e][tid];
  for (int j = 0; j < 64; j++) {
    int idx = base_i + j;
    int v = topk_idx[idx];
    int p = 0;
#pragma unroll
    for (int e = 0; e < NE; e++) if (v == e) p = pos[e]++;
    row_token[p] = idx >> 1;
    tokrow[idx] = p;
  }
}

// ---------------- grouped GEMM1: h = silu(x@gate^T) * (x@up^T), bf16 out ----------------
// BM=256 x BN=128, BK=64, 512 threads (8 waves as 4Mx2N, 64x64 per wave per matrix).
// Round-0's PROVEN staging pattern (8 lanes = 128B contiguous per row, XOR-swizzled
// 16B slot, linear LDS dest) + depth-1 counted pipeline with raw barriers:
//   STAGE(kt+1 -> buf^1) ; ds_read+MFMA(buf cur) ; vmcnt(0)+s_barrier
// One barrier per K-step, placed AFTER compute, so prefetch flies under the MFMAs.
__global__ __launch_bounds__(512, 2) void k_gemm1(
    const u16* __restrict__ xb, const u16* __restrict__ gwb, const u16* __restrict__ uwb,
    const int* __restrict__ meta, const int* __restrict__ row_token, u16* __restrict__ hb)
{
  int total = meta[8];
  int mt = (int)blockIdx.x;
  mt = (mt & 7) * 9 + (mt >> 3);     // chunked XCD swizzle, bijective (72 = 8*9)
  if (mt >= total) return;
  int e = meta[64 + mt];
  int row0 = meta[256 + mt];
  int ntile = blockIdx.y;

  __shared__ u16 As[2][BM * BK];     // 2 x 32KB, row-major [row][k], XOR slot swizzle
  __shared__ u16 Bg[2][BN1 * BK];    // 2 x 16KB
  __shared__ u16 Bu[2][BN1 * BK];    // 2 x 16KB  -> 128KB total static

  int lane = threadIdx.x & 63;
  int wave = threadIdx.x >> 6;       // 0..7
  int wr = wave >> 1, wc = wave & 1; // 4M x 2N

  // staging: thread's 16B chunk -> row r, swizzled slot c; 8 lanes cover 128B of a row
  const u16* aG[4]; unsigned aOff[4];
  const u16* gG[2]; const u16* uG[2]; unsigned bOff[2];
#pragma unroll
  for (int j = 0; j < 4; j++) {
    int r = wave * 32 + j * 8 + (lane >> 3);
    int c = (lane & 7) ^ (r & 7);
    int tok = row_token[row0 + r];
    aG[j] = xb + (size_t)tok * HD + c * 8;
    aOff[j] = (unsigned)(wave * 32 + j * 8) * 128;   // wave-uniform LDS base (bytes)
  }
#pragma unroll
  for (int j = 0; j < 2; j++) {
    int r = wave * 16 + j * 8 + (lane >> 3);
    int c = (lane & 7) ^ (r & 7);
    int nrow = ntile * BN1 + r;
    size_t wof = ((size_t)e * FD + nrow) * HD + c * 8;
    gG[j] = gwb + wof;
    uG[j] = uwb + wof;
    bOff[j] = (unsigned)(wave * 16 + j * 8) * 128;
  }

  f32x4 accG[4][4] = {};
  f32x4 accU[4][4] = {};

  // prologue: stage tile 0 into buffer 0
#pragma unroll
  for (int j = 0; j < 4; j++) async_copy16(aG[j], (char*)As[0] + aOff[j]);
#pragma unroll
  for (int j = 0; j < 2; j++) async_copy16(gG[j], (char*)Bg[0] + bOff[j]);
#pragma unroll
  for (int j = 0; j < 2; j++) async_copy16(uG[j], (char*)Bu[0] + bOff[j]);
  asm volatile("s_waitcnt vmcnt(0)" ::: "memory");
  __builtin_amdgcn_sched_barrier(0);
  __builtin_amdgcn_s_barrier();

  int cur = 0;
  for (int kt = 0; kt < HD / BK; kt++) {     // 32 K-steps
    if (kt + 1 < HD / BK) {                  // prefetch next tile into the other buffer
      int ko = (kt + 1) * BK;
#pragma unroll
      for (int j = 0; j < 4; j++) async_copy16(aG[j] + ko, (char*)As[cur ^ 1] + aOff[j]);
#pragma unroll
      for (int j = 0; j < 2; j++) async_copy16(gG[j] + ko, (char*)Bg[cur ^ 1] + bOff[j]);
#pragma unroll
      for (int j = 0; j < 2; j++) async_copy16(uG[j] + ko, (char*)Bu[cur ^ 1] + bOff[j]);
    }
#pragma unroll
    for (int kk = 0; kk < 2; kk++) {
      bf16x8 av[4], gv[4], uv[4];
#pragma unroll
      for (int mi = 0; mi < 4; mi++) {
        int r = wr * 64 + mi * 16 + (lane & 15);
        int slot = (kk * 4 + (lane >> 4)) ^ (r & 7);
        av[mi] = *(const bf16x8*)((const char*)As[cur] + (unsigned)(r * 8 + slot) * 16);
      }
#pragma unroll
      for (int ni = 0; ni < 4; ni++) {
        int r = wc * 64 + ni * 16 + (lane & 15);
        int slot = (kk * 4 + (lane >> 4)) ^ (r & 7);
        gv[ni] = *(const bf16x8*)((const char*)Bg[cur] + (unsigned)(r * 8 + slot) * 16);
        uv[ni] = *(const bf16x8*)((const char*)Bu[cur] + (unsigned)(r * 8 + slot) * 16);
      }
      __builtin_amdgcn_s_setprio(1);
#pragma unroll
      for (int mi = 0; mi < 4; mi++)
#pragma unroll
        for (int ni = 0; ni < 4; ni++) {
          accG[mi][ni] = __builtin_amdgcn_mfma_f32_16x16x32_bf16(av[mi], gv[ni], accG[mi][ni], 0, 0, 0);
          accU[mi][ni] = __builtin_amdgcn_mfma_f32_16x16x32_bf16(av[mi], uv[ni], accU[mi][ni], 0, 0, 0);
        }
      __builtin_amdgcn_s_setprio(0);
    }
    // single post-compute barrier: prefetch had the whole compute phase in flight
    asm volatile("s_waitcnt vmcnt(0)" ::: "memory");
    __builtin_amdgcn_sched_barrier(0);
    __builtin_amdgcn_s_barrier();
    cur ^= 1;
  }

  // epilogue: silu(g)*u -> bf16 h. D layout: col=lane&15, row=(lane>>4)*4+reg
#pragma unroll
  for (int mi = 0; mi < 4; mi++) {
#pragma unroll
    for (int r = 0; r < 4; r++) {
      int row = row0 + wr * 64 + mi * 16 + (lane >> 4) * 4 + r;
      u16* hrow = hb + (size_t)row * FD + ntile * BN1 + wc * 64 + (lane & 15);
#pragma unroll
      for (int ni = 0; ni < 4; ni++) {
        float g = accG[mi][ni][r];
        float u = accU[mi][ni][r];
        float s = g / (1.f + __expf(-g));
        hrow[ni * 16] = f2bf(s * u);
      }
    }
  }
}

// ---------------- grouped GEMM2: Y = h @ down^T (row space, bf16, plain stores) ----------------
// BM=256 x BN=128, BK=64, 512 threads (4Mx2N waves, 64x64 per wave). Same pipeline.
__global__ __launch_bounds__(512, 2) void k_gemm2(
    const u16* __restrict__ hb, const u16* __restrict__ dwb,
    const int* __restrict__ meta, u16* __restrict__ Y)
{
  int total = meta[8];
  int mt = (int)blockIdx.x;
  mt = (mt & 7) * 9 + (mt >> 3);     // chunked XCD swizzle (72 = 8*9)
  if (mt >= total) return;
  int e = meta[64 + mt];
  int row0 = meta[256 + mt];
  int ntile = blockIdx.y;            // 0..15

  __shared__ u16 As[2][BM * BK];     // 2 x 32KB
  __shared__ u16 Bs[2][BN2 * BK];    // 2 x 16KB  -> 96KB total static

  int lane = threadIdx.x & 63;
  int wave = threadIdx.x >> 6;
  int wr = wave >> 1, wc = wave & 1; // 4M x 2N

  const u16* aG[4]; unsigned aOff[4];
  const u16* bG[2]; unsigned bOff[2];
#pragma unroll
  for (int j = 0; j < 4; j++) {
    int r = wave * 32 + j * 8 + (lane >> 3);
    int c = (lane & 7) ^ (r & 7);
    aG[j] = hb + (size_t)(row0 + r) * FD + c * 8;
    aOff[j] = (unsigned)(wave * 32 + j * 8) * 128;
  }
#pragma unroll
  for (int j = 0; j < 2; j++) {
    int r = wave * 16 + j * 8 + (lane >> 3);
    int c = (lane & 7) ^ (r & 7);
    int nrow = ntile * BN2 + r;
    bG[j] = dwb + ((size_t)e * HD + nrow) * FD + c * 8;
    bOff[j] = (unsigned)(wave * 16 + j * 8) * 128;
  }

  f32x4 acc[4][4] = {};

  // prologue
#pragma unroll
  for (int j = 0; j < 4; j++) async_copy16(aG[j], (char*)As[0] + aOff[j]);
#pragma unroll
  for (int j = 0; j < 2; j++) async_copy16(bG[j], (char*)Bs[0] + bOff[j]);
  asm volatile("s_waitcnt vmcnt(0)" ::: "memory");
  __builtin_amdgcn_sched_barrier(0);
  __builtin_amdgcn_s_barrier();

  int cur = 0;
  for (int kt = 0; kt < FD / BK; kt++) {     // 22 K-steps
    if (kt + 1 < FD / BK) {
      int ko = (kt + 1) * BK;
#pragma unroll
      for (int j = 0; j < 4; j++) async_copy16(aG[j] + ko, (char*)As[cur ^ 1] + aOff[j]);
#pragma unroll
      for (int j = 0; j < 2; j++) async_copy16(bG[j] + ko, (char*)Bs[cur ^ 1] + bOff[j]);
    }
#pragma unroll
    for (int kk = 0; kk < 2; kk++) {
      bf16x8 av[4], bv[4];
#pragma unroll
      for (int mi = 0; mi < 4; mi++) {
        int r = wr * 64 + mi * 16 + (lane & 15);
        int slot = (kk * 4 + (lane >> 4)) ^ (r & 7);
        av[mi] = *(const bf16x8*)((const char*)As[cur] + (unsigned)(r * 8 + slot) * 16);
      }
#pragma unroll
      for (int ni = 0; ni < 4; ni++) {
        int r = wc * 64 + ni * 16 + (lane & 15);
        int slot = (kk * 4 + (lane >> 4)) ^ (r & 7);
        bv[ni] = *(const bf16x8*)((const char*)Bs[cur] + (unsigned)(r * 8 + slot) * 16);
      }
      __builtin_amdgcn_s_setprio(1);
#pragma unroll
      for (int mi = 0; mi < 4; mi++)
#pragma unroll
        for (int ni = 0; ni < 4; ni++)
          acc[mi][ni] = __builtin_amdgcn_mfma_f32_16x16x32_bf16(av[mi], bv[ni], acc[mi][ni], 0, 0, 0);
      __builtin_amdgcn_s_setprio(0);
    }
    asm volatile("s_waitcnt vmcnt(0)" ::: "memory");
    __builtin_amdgcn_sched_barrier(0);
    __builtin_amdgcn_s_barrier();
    cur ^= 1;
  }

  // epilogue: plain bf16 stores into row-space Y
#pragma unroll
  for (int mi = 0; mi < 4; mi++) {
#pragma unroll
    for (int r = 0; r < 4; r++) {
      int grow = row0 + wr * 64 + mi * 16 + (lane >> 4) * 4 + r;
      u16* yrow = Y + (size_t)grow * HD + ntile * BN2 + wc * 64 + (lane & 15);
#pragma unroll
      for (int ni = 0; ni < 4; ni++)
        yrow[ni * 16] = f2bf(acc[mi][ni][r]);
    }
  }
}

// ---------------- combine: out[t] = wA*Y[rowA] + wB*Y[rowB] ----------------
__global__ __launch_bounds__(256) void k_combine(
    const u16* __restrict__ Y, const int* __restrict__ tokrow,
    const float* __restrict__ topk_w, float* __restrict__ out)
{
  int t = blockIdx.x;
  int i = threadIdx.x;               // 256 threads x 8 cols = 2048
  int rA = tokrow[t * 2], rB = tokrow[t * 2 + 1];
  float wA = topk_w[t * 2], wB = topk_w[t * 2 + 1];
  uint4 a = *(const uint4*)(Y + (size_t)rA * HD + i * 8);
  uint4 b = *(const uint4*)(Y + (size_t)rB * HD + i * 8);
  float4 o0, o1;
  o0.x = wA * bflo(a.x) + wB * bflo(b.x);
  o0.y = wA * bfhi(a.x) + wB * bfhi(b.x);
  o0.z = wA * bflo(a.y) + wB * bflo(b.y);
  o0.w = wA * bfhi(a.y) + wB * bfhi(b.y);
  o1.x = wA * bflo(a.z) + wB * bflo(b.z);
  o1.y = wA * bfhi(a.z) + wB * bfhi(b.z);
  o1.z = wA * bflo(a.w) + wB * bflo(b.w);
  o1.w = wA * bfhi(a.w) + wB * bfhi(b.w);
  float* op = out + (size_t)t * HD + i * 8;
  *(float4*)op = o0;
  *(float4*)(op + 4) = o1;
}

extern "C" void kernel_launch(void* const* d_in, const int* in_sizes, int n_in,
                              void* d_out, int out_size, void* d_ws, size_t ws_size,
                              hipStream_t stream) {
  const float* x  = (const float*)d_in[0];
  const float* rw = (const float*)d_in[1];
  const float* gw = (const float*)d_in[2];
  const float* uw = (const float*)d_in[3];
  const float* dw = (const float*)d_in[4];
  float* out = (float*)d_out;

  char* w = (char*)d_ws;
  int*   meta      = (int*)w;                                    // 4KB meta block
  int*   row_token = (int*)(w + 4096);
  int*   topk_idx  = (int*)(w + 4096 + ROWS_CAP * 4);
  float* topk_w    = (float*)(w + 4096 + ROWS_CAP * 4 + T_TOK * 2 * 4);
  int*   tokrow    = (int*)(w + 4096 + ROWS_CAP * 4 + T_TOK * 4 * 4);
  size_t off = (size_t)1 << 20;
  u16* xb  = (u16*)(w + off); off += (size_t)T_TOK * HD * 2;     // 33.5 MB
  u16* gwb = (u16*)(w + off); off += (size_t)NE * FD * HD * 2;   // 46.1 MB
  u16* uwb = (u16*)(w + off); off += (size_t)NE * FD * HD * 2;   // 46.1 MB
  u16* dwb = (u16*)(w + off); off += (size_t)NE * HD * FD * 2;   // 46.1 MB
  u16* hb  = (u16*)(w + off);                                    // 51.9 MB
  // Y (75.5 MB) aliases xb+gwb (79.7 MB) — both dead once gemm1 completes,
  // and the stream serializes gemm1 -> gemm2 -> combine.
  u16* Y = xb;

  k_router<<<T_TOK, 256, 0, stream>>>(x, rw, gw, uw, dw, xb, gwb, uwb, dwb, topk_idx, topk_w);
  k_meta_scatter<<<1, 256, 0, stream>>>(topk_idx, meta, row_token, tokrow);
  k_gemm1<<<dim3(MAXT, FD / BN1), 512, 0, stream>>>(xb, gwb, uwb, meta, row_token, hb);
  k_gemm2<<<dim3(MAXT, HD / BN2), 512, 0, stream>>>(hb, dwb, meta, Y);
  k_combine<<<T_TOK, 256, 0, stream>>>(Y, tokrow, topk_w, out);
}